// Round 10
// baseline (153.936 us; speedup 1.0000x reference)
//
#include <hip/hip_runtime.h>
#include <math.h>

#define B_TOT 2048
#define R_TOT 512
#define D_TOT 256
#define LOG2E 1.4426950408889634f
#define MAGIC 12582912.0f   // 1.5 * 2^23: round-to-nearest magic for |t| < 2^22

typedef float vf4 __attribute__((ext_vector_type(4)));
typedef float vf2 __attribute__((ext_vector_type(2)));

// gated = (1 + m1*e)/(1 + e),  e = exp2(A*x + Bc)
// A = -log2e*kappa*tanh(sign), Bc = -A*th, m1 = 1 - sigmoid(mask)
// |t| <= ~20 in practice -> e in [2^-20, 2^20]; den4 <= 2^84, np4 <= 2^70:
// fp32-safe without rescaling (proven rounds 5-9).

// DPP cross-lane: xor1 = quad_perm [1,0,3,2] = 0xB1; xor2 = [2,3,0,1] = 0x4E
static __device__ __forceinline__ float dpp_xor1(float v) {
    int i = __builtin_amdgcn_mov_dpp(__float_as_int(v), 0xB1, 0xF, 0xF, true);
    return __int_as_float(i);
}
static __device__ __forceinline__ float dpp_xor2(float v) {
    int i = __builtin_amdgcn_mov_dpp(__float_as_int(v), 0x4E, 0xF, 0xF, true);
    return __int_as_float(i);
}
// trans versions: used only for the once-per-wave param computation
static __device__ __forceinline__ vf4 exp2v_trans(vf4 t) {
    vf4 e;
    e.x = __builtin_amdgcn_exp2f(t.x);
    e.y = __builtin_amdgcn_exp2f(t.y);
    e.z = __builtin_amdgcn_exp2f(t.z);
    e.w = __builtin_amdgcn_exp2f(t.w);
    return e;
}
static __device__ __forceinline__ vf4 rcpv(vf4 t) {
    vf4 e;
    e.x = __builtin_amdgcn_rcpf(t.x);
    e.y = __builtin_amdgcn_rcpf(t.y);
    e.z = __builtin_amdgcn_rcpf(t.z);
    e.w = __builtin_amdgcn_rcpf(t.w);
    return e;
}

// ---------------------------------------------------------------------------
// VALU exp2: round-10 lever. Trans v_exp_f32 blocks the issue port 16 cy
// (sum-model fit, rounds 5/8/9); this poly does the same work in ~30 cy of
// packed/full-rate VALU for 4 elements (vs 64 cy for 4 trans ops).
//   tc = t + 1.5*2^23  -> low mantissa bits hold round-to-nearest(t)
//   f  = t - (tc - C) in [-0.5, 0.5]
//   p  = 2^f  (deg-5 Taylor, rel err <= 3.4e-6)
//   e  = p * 2^n  via as_int(p) + (as_int(tc) << 23)   [exact: low 9 bits of
//        0x4B400000 are 0, n in [-60,60] keeps exponent valid]
// ---------------------------------------------------------------------------
static __device__ __forceinline__ vf4 exp2v_poly(vf4 t) {
    vf4 tc = t + MAGIC;
    vf4 r  = tc - MAGIC;
    vf4 f  = t - r;
    vf4 p  = ((((0.0013333558f * f + 0.0096181291f) * f + 0.0555041087f) * f
               + 0.2402265070f) * f + 0.6931471806f) * f + 1.0f;
    vf4 e;
    e.x = __int_as_float(__float_as_int(p.x) + (__float_as_int(tc.x) << 23));
    e.y = __int_as_float(__float_as_int(p.y) + (__float_as_int(tc.y) << 23));
    e.z = __int_as_float(__float_as_int(p.z) + (__float_as_int(tc.z) << 23));
    e.w = __int_as_float(__float_as_int(p.w) + (__float_as_int(tc.w) << 23));
    return e;
}

// ---------------------------------------------------------------------------
// Round 10 = round-9 structure (wave: 4 rules x 4 batches/group, zero
// barriers, 1 atomic/(WG,batch)) + poly exp2 + fused param computation
// (prep dispatch deleted).
//  - __launch_bounds__(256,4): (256,8) caps VGPR at 32 and spills (r4/r7!)
//  - prefetch pinned with sched_barrier(0) (r6: unpinned prefetch re-sinks)
// grid (128,16) = 2048 WGs = 8/CU, long-lived.
// ---------------------------------------------------------------------------
__global__ __launch_bounds__(256, 4) void main_kernel(
        const float* __restrict__ x,       // [B_TOT][D_TOT]
        const float* __restrict__ th,      // [R_TOT][D_TOT]
        const float* __restrict__ sp,      // [R_TOT][D_TOT]
        const float* __restrict__ ml,      // [R_TOT][D_TOT]
        const float* __restrict__ lk,      // [1]
        const float* __restrict__ head_w,  // [R_TOT]
        const float* __restrict__ head_b,  // [1]
        float*       __restrict__ y) {     // [B_TOT]
    __shared__ float rbuf[4][16][36];      // wave-private; rows 16B-aligned

    const int tid   = threadIdx.x;
    const int lane  = tid & 63;
    const int wave  = tid >> 6;
    const int rbase = blockIdx.x << 2;     // 4 rules per WG (shared by waves)
    const int bgg0  = blockIdx.y << 3;     // 8 groups of 16 batches

    // ---- params: computed once per wave, live in VGPRs ----
    const float kmul = -LOG2E * __builtin_amdgcn_exp2f(lk[0] * LOG2E);
    vf4 A[4], Bc[4], Ms[4];
    #pragma unroll
    for (int j = 0; j < 4; j++) {
        size_t pidx = (size_t)(rbase + j) * 64 + lane;
        vf4 u  = ((const vf4*)sp)[pidx];
        vf4 eu = exp2v_trans((2.0f * LOG2E) * u);
        vf4 tt = 1.0f - 2.0f * rcpv(eu + 1.0f);     // tanh(u)
        A[j]  = kmul * tt;
        Bc[j] = (-A[j]) * ((const vf4*)th)[pidx];
        vf4 em = exp2v_trans(LOG2E * ((const vf4*)ml)[pidx]);
        Ms[j] = rcpv(1.0f + em);                    // m1 = 1 - sigmoid(ml)
    }
    // per-lane head weight for the end-phase (lane&3 selects the rule)
    float w0 = head_w[rbase], w1 = head_w[rbase + 1];
    float w2 = head_w[rbase + 2], w3 = head_w[rbase + 3];
    int lj = lane & 3;
    float wsel = (lj == 0) ? w0 : ((lj == 1) ? w1 : ((lj == 2) ? w2 : w3));
    const float bias = (blockIdx.x == 0) ? head_b[0] : 0.0f;

    // x base for this wave's 4 batch rows; row stride 64 vf4, group 1024 vf4
    const vf4* xbase = (const vf4*)x
                       + ((size_t)(bgg0 * 16 + (wave << 2))) * 64 + lane;

    vf4 cur[4], nxt[4];
    #pragma unroll
    for (int i = 0; i < 4; i++) cur[i] = xbase[i * 64];

    #pragma unroll 1
    for (int g = 0; g < 8; g++) {
        // ---- prefetch next group's 4 rows (pinned before compute) ----
        int gn = (g < 7) ? g + 1 : 7;
        #pragma unroll
        for (int i = 0; i < 4; i++) nxt[i] = xbase[gn * 1024 + i * 64];
        __builtin_amdgcn_sched_barrier(0);

        // ---- 16 rows: (batch i, rule j) ----
        #pragma unroll
        for (int i = 0; i < 4; i++) {
            vf4 xb = cur[i];
            #pragma unroll
            for (int j = 0; j < 4; j++) {
                vf4 t  = A[j] * xb + Bc[j];     // v_pk_fma_f32
                vf4 e  = exp2v_poly(t);         // VALU-only exp2
                vf4 n  = Ms[j] * e + 1.0f;      // numerator factors
                vf4 dd = e + 1.0f;              // denominator factors
                vf2 hn = n.lo * n.hi;
                vf2 hd = dd.lo * dd.hi;
                float np = hn.x * hn.y;
                float dp = hd.x * hd.y;
                float r4 = np * __builtin_amdgcn_rcpf(dp);  // 4-d ratio
                float r8 = r4 * dpp_xor1(r4);   // 8-d (lane-pair) ratio
                if (!(lane & 1))
                    rbuf[wave][i * 4 + j][lane >> 1] = r8;
            }
        }

        // ---- end-phase (wave-private, no barrier): row l = (b=l>>2, r=l&3)
        if (lane < 16) {
            const float* rb = &rbuf[wave][lane][0];
            vf4 a0 = *(const vf4*)(rb)      * *(const vf4*)(rb + 4);
            vf4 a1 = *(const vf4*)(rb + 8)  * *(const vf4*)(rb + 12);
            vf4 a2 = *(const vf4*)(rb + 16) * *(const vf4*)(rb + 20);
            vf4 a3 = *(const vf4*)(rb + 24) * *(const vf4*)(rb + 28);
            vf4 m  = (a0 * a1) * (a2 * a3);
            vf2 h  = m.lo * m.hi;
            float z  = h.x * h.y;               // z(batch, rule)
            float t  = wsel * z;                // w[r] * z
            float t1 = t + dpp_xor1(t);         // sum over rule pairs
            float t2 = t1 + dpp_xor2(t1);       // full 4-rule sum at lane 4i
            if ((lane & 3) == 0) {
                int b = ((bgg0 + g) << 4) + (wave << 2) + (lane >> 2);
                atomicAdd(&y[b], t2 + bias);    // bias once: only bx==0 WGs
            }
        }

        #pragma unroll
        for (int i = 0; i < 4; i++) cur[i] = nxt[i];
    }
}

extern "C" void kernel_launch(void* const* d_in, const int* in_sizes, int n_in,
                              void* d_out, int out_size, void* d_ws, size_t ws_size,
                              hipStream_t stream) {
    const float* x  = (const float*)d_in[0];
    const float* th = (const float*)d_in[1];
    const float* sp = (const float*)d_in[2];
    const float* ml = (const float*)d_in[3];
    const float* lk = (const float*)d_in[4];
    const float* hw = (const float*)d_in[5];
    const float* hb = (const float*)d_in[6];
    float* y = (float*)d_out;

    hipMemsetAsync(y, 0, (size_t)out_size * sizeof(float), stream);
    dim3 grid(R_TOT / 4, B_TOT / 128, 1);   // (128, 16) = 2048 WGs = 8/CU
    main_kernel<<<grid, 256, 0, stream>>>(x, th, sp, ml, lk, hw, hb, y);
}